// Round 2
// baseline (72.778 us; speedup 1.0000x reference)
//
#include <hip/hip_runtime.h>

// Problem constants (from reference)
#define BATCH 64
#define LEXPR 8192
#define FSUB  100
#define VOCAB 64
#define NPOS  (LEXPR + 1)   // 8193 valid conv positions
#define NSEG  8             // segments per row -> 512 blocks total
#define SEG   1025          // ceil(NPOS / NSEG)
#define TPB   256

// Each block fully owns positions [p0, p1) of one row: it reads expr[j] for
// j in [p0, min(p1+99, 8192)) and scatters score[p]++ for p = j - f whenever
// sub[f] == expr[j] (f encoded as per-vocab 100-bit masks; PAD=0 filtered).
// Packed key (score<<14)|(16383-p): max key == max score, ties -> smallest p
// (matches jnp.argmax first-occurrence). One global atomicMax per block per
// row; last block (device-scope counter) writes the 128 output floats.
__global__ __launch_bounds__(TPB)
void Finder_66640712565346_kernel(const int* __restrict__ expr,
                                  const int* __restrict__ sub,
                                  unsigned int* __restrict__ keys,    // [BATCH]
                                  unsigned int* __restrict__ counter, // [1]
                                  float* __restrict__ out) {
    __shared__ unsigned int mask[VOCAB][4];   // 100 bits of sub positions per vocab value
    __shared__ unsigned int score[SEG];
    __shared__ unsigned int red[TPB / 64];
    __shared__ unsigned int is_last;

    const int seg = blockIdx.x;
    const int b   = blockIdx.y;
    const int tid = threadIdx.x;
    const int p0  = seg * SEG;
    const int p1  = min(p0 + SEG, NPOS);
    const int nloc = p1 - p0;

    for (int i = tid; i < VOCAB * 4; i += TPB) ((unsigned int*)mask)[i] = 0u;
    for (int i = tid; i < SEG; i += TPB) score[i] = 0u;
    __syncthreads();

    if (tid < FSUB) {
        int v = sub[b * FSUB + tid];
        if (v != 0) atomicOr(&mask[v][tid >> 5], 1u << (tid & 31));
    }
    __syncthreads();

    // j range needed for positions [p0, p1): j = p + f, f in [0, 99]
    const int jend = min(p1 + FSUB - 1, LEXPR);  // exclusive
    const int* erow = expr + b * LEXPR;
    for (int j = p0 + tid; j < jend; j += TPB) {
        int v = erow[j];
        unsigned int m0 = mask[v][0];
        unsigned int m1 = mask[v][1];
        unsigned int m2 = mask[v][2];
        unsigned int m3 = mask[v][3];
        while (m0) { int f =      __builtin_ctz(m0); m0 &= m0 - 1u; int p = j - f; if (p >= p0 && p < p1) atomicAdd(&score[p - p0], 1u); }
        while (m1) { int f = 32 + __builtin_ctz(m1); m1 &= m1 - 1u; int p = j - f; if (p >= p0 && p < p1) atomicAdd(&score[p - p0], 1u); }
        while (m2) { int f = 64 + __builtin_ctz(m2); m2 &= m2 - 1u; int p = j - f; if (p >= p0 && p < p1) atomicAdd(&score[p - p0], 1u); }
        while (m3) { int f = 96 + __builtin_ctz(m3); m3 &= m3 - 1u; int p = j - f; if (p >= p0 && p < p1) atomicAdd(&score[p - p0], 1u); }
    }
    __syncthreads();

    // Local packed-key max over this segment's positions
    unsigned int best = 0u;
    for (int i = tid; i < nloc; i += TPB) {
        unsigned int k = (score[i] << 14) | (16383u - (unsigned int)(p0 + i));
        if (k > best) best = k;
    }
    #pragma unroll
    for (int off = 32; off > 0; off >>= 1) {
        unsigned int o = __shfl_down(best, off, 64);
        if (o > best) best = o;
    }
    if ((tid & 63) == 0) red[tid >> 6] = best;
    __syncthreads();

    if (tid == 0) {
        unsigned int bb = red[0];
        #pragma unroll
        for (int w = 1; w < TPB / 64; ++w) if (red[w] > bb) bb = red[w];
        atomicMax(&keys[b], bb);
        __threadfence();  // make key visible before signaling completion
        unsigned int done = atomicAdd(counter, 1u);
        is_last = (done == (unsigned int)(NSEG * BATCH - 1)) ? 1u : 0u;
    }
    __syncthreads();

    if (is_last && tid < BATCH) {
        __threadfence();
        // atomic read-modify-write with identity -> coherent cross-XCD read
        unsigned int k = atomicAdd(&keys[tid], 0u);
        out[tid]         = (float)(16383u - (k & 16383u));  // position
        out[BATCH + tid] = (float)(k >> 14);                // max score
    }
}

extern "C" void kernel_launch(void* const* d_in, const int* in_sizes, int n_in,
                              void* d_out, int out_size, void* d_ws, size_t ws_size,
                              hipStream_t stream) {
    const int* expr = (const int*)d_in[0];  // [64, 8192] int32
    const int* sub  = (const int*)d_in[1];  // [64, 100] int32
    float* out = (float*)d_out;             // [64] positions ++ [64] max scores

    unsigned int* keys    = (unsigned int*)d_ws;   // [BATCH]
    unsigned int* counter = keys + BATCH;          // [1]

    // d_ws is poisoned to 0xAA before every call: zero keys + counter.
    hipMemsetAsync(d_ws, 0, (BATCH + 1) * sizeof(unsigned int), stream);

    dim3 grid(NSEG, BATCH);
    Finder_66640712565346_kernel<<<grid, TPB, 0, stream>>>(expr, sub, keys, counter, out);
}

// Round 3
// 63.277 us; speedup vs baseline: 1.1502x; 1.1502x over previous
//
#include <hip/hip_runtime.h>

// Problem constants (from reference)
#define BATCH 64
#define LEXPR 8192
#define FSUB  100
#define VOCAB 64
#define NPOS  (LEXPR + 1)   // 8193 valid conv positions
#define TPB   1024

// One block per batch row. Scatter formulation: both sides are one-hot, so
// score[p] = #{f : sub[f]==expr[p+f], sub[f]!=PAD}. Per-vocab 100-bit masks of
// sub positions; each expr element j generates ~1.5 LDS score[j-f]++ atomics.
// Packed key (score<<14)|(16383-p): max key == max score, ties -> smallest p
// (first-occurrence argmax, matching jnp.argmax).
__global__ __launch_bounds__(TPB)
void Finder_66640712565346_kernel(const int* __restrict__ expr,
                                  const int* __restrict__ sub,
                                  float* __restrict__ out) {
    __shared__ unsigned int mask[VOCAB][4];                 // 100 bits per vocab value
    __shared__ __align__(16) unsigned int score[NPOS];      // 32.8 KB
    __shared__ unsigned int wred[TPB / 64];

    const int b   = blockIdx.x;
    const int tid = threadIdx.x;

    // Zero score (uint4-wide: 8192 = 2048 x uint4, +1 tail) and masks
    {
        uint4* s4 = (uint4*)score;
        uint4 z = make_uint4(0u, 0u, 0u, 0u);
        s4[tid] = z;
        s4[tid + TPB] = z;
        if (tid == 0) score[LEXPR] = 0u;
        if (tid < VOCAB * 4) ((unsigned int*)mask)[tid] = 0u;
    }
    __syncthreads();

    // Build per-vocab bitmasks from sub_expression; PAD (0) contributes nothing.
    if (tid < FSUB) {
        int v = sub[b * FSUB + tid];
        if (v != 0) atomicOr(&mask[v][tid >> 5], 1u << (tid & 31));
    }
    __syncthreads();

    // Scatter: two int4 loads per thread cover all 8192 expr elements.
    const int4* erow4 = (const int4*)(expr + b * LEXPR);
    #pragma unroll
    for (int it = 0; it < 2; ++it) {
        int idx = tid + it * TPB;          // int4 index
        int4 v4 = erow4[idx];
        int jbase = idx * 4;
        #pragma unroll
        for (int e = 0; e < 4; ++e) {
            int v = (e == 0) ? v4.x : (e == 1) ? v4.y : (e == 2) ? v4.z : v4.w;
            int j = jbase + e;
            unsigned int m0 = mask[v][0];
            unsigned int m1 = mask[v][1];
            unsigned int m2 = mask[v][2];
            unsigned int m3 = mask[v][3];
            while (m0) { int f =      __builtin_ctz(m0); m0 &= m0 - 1u; int p = j - f; if (p >= 0) atomicAdd(&score[p], 1u); }
            while (m1) { int f = 32 + __builtin_ctz(m1); m1 &= m1 - 1u; int p = j - f; if (p >= 0) atomicAdd(&score[p], 1u); }
            while (m2) { int f = 64 + __builtin_ctz(m2); m2 &= m2 - 1u; int p = j - f; if (p >= 0) atomicAdd(&score[p], 1u); }
            while (m3) { int f = 96 + __builtin_ctz(m3); m3 &= m3 - 1u; int p = j - f; if (p >= 0) atomicAdd(&score[p], 1u); }
        }
    }
    __syncthreads();

    // Packed-key max: score<=100 (7 bits) << 14 | (16383 - p), p<=8192 (14 bits)
    unsigned int best = 0u;
    for (int p = tid; p < NPOS; p += TPB) {
        unsigned int k = (score[p] << 14) | (16383u - (unsigned int)p);
        if (k > best) best = k;
    }
    // Wave-level shuffle reduction (64 lanes)
    #pragma unroll
    for (int off = 32; off > 0; off >>= 1) {
        unsigned int o = __shfl_down(best, off, 64);
        if (o > best) best = o;
    }
    if ((tid & 63) == 0) wred[tid >> 6] = best;
    __syncthreads();
    if (tid == 0) {
        unsigned int k = wred[0];
        #pragma unroll
        for (int w = 1; w < TPB / 64; ++w) if (wred[w] > k) k = wred[w];
        out[b]         = (float)(16383u - (k & 16383u));  // position
        out[BATCH + b] = (float)(k >> 14);                // max score
    }
}

extern "C" void kernel_launch(void* const* d_in, const int* in_sizes, int n_in,
                              void* d_out, int out_size, void* d_ws, size_t ws_size,
                              hipStream_t stream) {
    const int* expr = (const int*)d_in[0];  // [64, 8192] int32
    const int* sub  = (const int*)d_in[1];  // [64, 100] int32
    float* out = (float*)d_out;             // [64] positions ++ [64] max scores

    Finder_66640712565346_kernel<<<BATCH, TPB, 0, stream>>>(expr, sub, out);
}